// Round 4
// baseline (187.031 us; speedup 1.0000x reference)
//
#include <hip/hip_runtime.h>

// QCausalConv1D: int8 depthwise causal conv1d (K=4) + bias + SiLU + requant.
// B=8, D=4096, L=4096. Inputs widened to int32; output read back as int32.
//
// Memory-bound: 512 MiB x-read + 512 MiB out-write (incompressible).
// R2: 214us grid-stride. R3: 180.8us (5.94 TB/s = 94% of 6.29 TB/s copy ceiling).
// R4: eliminate the prev-vector reloads via __shfl_up — x read exactly once;
// only wave-boundary lanes (4/256) load their neighbor vector from memory.

#define Dq 4096
#define VPR 1024          // int4 vectors per row (L=4096 / 4)

typedef int int4v __attribute__((ext_vector_type(4)));

__global__ void __launch_bounds__(256)
qconv1d_kernel(const int* __restrict__ x,       // (B, D, L) int32 in [-128,127]
               const int* __restrict__ w,       // (D, K=4)
               const int* __restrict__ bias,    // (D,)
               const float* __restrict__ s_in,
               const float* __restrict__ s_w,
               const float* __restrict__ s_out,
               const float* __restrict__ s_b,
               int* __restrict__ out) {
    const int row  = blockIdx.x;                // b*D + d
    const int d    = row & (Dq - 1);
    const int t    = threadIdx.x;
    const long base = (long)row * VPR;

    const int4v* __restrict__ xv = (const int4v*)x;
    const int4v* __restrict__ wv = (const int4v*)w;
    int4v* __restrict__ ov = (int4v*)out;

    // Coalesced stride-16B loads: thread t owns vectors g*256+t, g=0..3.
    int4v cur0 = xv[base + 0 * 256 + t];
    int4v cur1 = xv[base + 1 * 256 + t];
    int4v cur2 = xv[base + 2 * 256 + t];
    int4v cur3 = xv[base + 3 * 256 + t];

    // prev vector = neighbor lane's cur (shfl_up 1). Wave-boundary lanes
    // ((t&63)==0) can't reach the previous wave -> direct 16B load (L1/L2 hit).
    int4v prev0, prev1, prev2, prev3;
    #pragma unroll
    for (int c = 0; c < 4; ++c) {
        prev0[c] = __shfl_up(cur0[c], 1);
        prev1[c] = __shfl_up(cur1[c], 1);
        prev2[c] = __shfl_up(cur2[c], 1);
        prev3[c] = __shfl_up(cur3[c], 1);
    }
    if ((t & 63) == 0) {
        int4v zero = {0, 0, 0, 0};
        prev0 = (t == 0) ? zero : xv[base + 0 * 256 + t - 1];
        prev1 = xv[base + 1 * 256 + t - 1];
        prev2 = xv[base + 2 * 256 + t - 1];
        prev3 = xv[base + 3 * 256 + t - 1];
    }

    const int4v wt = wv[d];                     // taps w[d][0..3] (L2-resident)
    const float sc      = s_in[0] * s_w[0];
    const float inv_out = 1.0f / s_out[0];
    const float bf      = (float)bias[d] * s_b[0];

    int4v o0, o1, o2, o3;
    #pragma unroll
    for (int g = 0; g < 4; ++g) {
        int4v cur  = (g == 0) ? cur0  : (g == 1) ? cur1  : (g == 2) ? cur2  : cur3;
        int4v prev = (g == 0) ? prev0 : (g == 1) ? prev1 : (g == 2) ? prev2 : prev3;
        int xs[8] = {prev[0], prev[1], prev[2], prev[3],
                     cur[0],  cur[1],  cur[2],  cur[3]};
        int4v o;
        #pragma unroll
        for (int j = 0; j < 4; ++j) {
            // y[l] = x[l-3]*w0 + x[l-2]*w1 + x[l-1]*w2 + x[l]*w3
            int s = xs[j + 1] * wt[0] + xs[j + 2] * wt[1]
                  + xs[j + 3] * wt[2] + xs[j + 4] * wt[3];
            float y = (float)s * sc + bf;
            float sig = 1.0f / (1.0f + __expf(-y));
            float sil = y * sig;
            float q = rintf(sil * inv_out);      // round-half-even = jnp.round
            q = fminf(fmaxf(q, -128.0f), 127.0f);
            o[j] = (int)q;
        }
        if (g == 0) o0 = o; else if (g == 1) o1 = o; else if (g == 2) o2 = o; else o3 = o;
    }

    __builtin_nontemporal_store(o0, &ov[base + 0 * 256 + t]);
    __builtin_nontemporal_store(o1, &ov[base + 1 * 256 + t]);
    __builtin_nontemporal_store(o2, &ov[base + 2 * 256 + t]);
    __builtin_nontemporal_store(o3, &ov[base + 3 * 256 + t]);
}

extern "C" void kernel_launch(void* const* d_in, const int* in_sizes, int n_in,
                              void* d_out, int out_size, void* d_ws, size_t ws_size,
                              hipStream_t stream) {
    const int*   x    = (const int*)d_in[0];
    const int*   w    = (const int*)d_in[1];
    const int*   bias = (const int*)d_in[2];
    const float* s_in = (const float*)d_in[3];
    const float* s_w  = (const float*)d_in[4];
    const float* s_out= (const float*)d_in[5];
    const float* s_b  = (const float*)d_in[6];
    int* out = (int*)d_out;

    const int rows = out_size / (VPR * 4);      // B*D = 32768
    qconv1d_kernel<<<rows, 256, 0, stream>>>(x, w, bias, s_in, s_w, s_out, s_b, out);
}

// Round 5
// 181.964 us; speedup vs baseline: 1.0278x; 1.0278x over previous
//
#include <hip/hip_runtime.h>

// QCausalConv1D: int8 depthwise causal conv1d (K=4) + bias + SiLU + requant.
// B=8, D=4096, L=4096. Inputs widened to int32; output read back as int32.
//
// Memory-bound: 512 MiB x-read + 512 MiB out-write (incompressible).
// R2: 214us grid-stride. R3: 180.8us (5.94 TB/s = 94% of 6.29 TB/s copy ceiling).
// R4: shfl_up for prev REGRESSED (187us) — prev reloads are L1 hits on lines the
// wave already streams (free); shfl added critical-path latency. Reverted to R3.

#define Dq 4096
#define VPR 1024          // int4 vectors per row (L=4096 / 4)

typedef int int4v __attribute__((ext_vector_type(4)));

__global__ void __launch_bounds__(256)
qconv1d_kernel(const int* __restrict__ x,       // (B, D, L) int32 in [-128,127]
               const int* __restrict__ w,       // (D, K=4)
               const int* __restrict__ bias,    // (D,)
               const float* __restrict__ s_in,
               const float* __restrict__ s_w,
               const float* __restrict__ s_out,
               const float* __restrict__ s_b,
               int* __restrict__ out) {
    const int row  = blockIdx.x;                // b*D + d
    const int d    = row & (Dq - 1);
    const int t    = threadIdx.x;
    const long base = (long)row * VPR;

    const int4v* __restrict__ xv = (const int4v*)x;
    const int4v* __restrict__ wv = (const int4v*)w;
    int4v* __restrict__ ov = (int4v*)out;

    // Issue all 8 row loads up front for maximum memory-level parallelism.
    int4v cur0 = xv[base + 0 * 256 + t];
    int4v cur1 = xv[base + 1 * 256 + t];
    int4v cur2 = xv[base + 2 * 256 + t];
    int4v cur3 = xv[base + 3 * 256 + t];
    int4v zero = {0, 0, 0, 0};
    int4v prev0 = (t == 0) ? zero : xv[base + 0 * 256 + t - 1];
    int4v prev1 = xv[base + 1 * 256 + t - 1];
    int4v prev2 = xv[base + 2 * 256 + t - 1];
    int4v prev3 = xv[base + 3 * 256 + t - 1];

    const int4v wt = wv[d];                     // taps w[d][0..3] (L2-resident)
    const float sc      = s_in[0] * s_w[0];
    const float inv_out = 1.0f / s_out[0];
    const float bf      = (float)bias[d] * s_b[0];

    int4v o0, o1, o2, o3;
    #pragma unroll
    for (int g = 0; g < 4; ++g) {
        int4v cur  = (g == 0) ? cur0  : (g == 1) ? cur1  : (g == 2) ? cur2  : cur3;
        int4v prev = (g == 0) ? prev0 : (g == 1) ? prev1 : (g == 2) ? prev2 : prev3;
        int xs[8] = {prev[0], prev[1], prev[2], prev[3],
                     cur[0],  cur[1],  cur[2],  cur[3]};
        int4v o;
        #pragma unroll
        for (int j = 0; j < 4; ++j) {
            // y[l] = x[l-3]*w0 + x[l-2]*w1 + x[l-1]*w2 + x[l]*w3
            int s = xs[j + 1] * wt[0] + xs[j + 2] * wt[1]
                  + xs[j + 3] * wt[2] + xs[j + 4] * wt[3];
            float y = (float)s * sc + bf;
            float sig = 1.0f / (1.0f + __expf(-y));
            float sil = y * sig;
            float q = rintf(sil * inv_out);      // round-half-even = jnp.round
            q = fminf(fmaxf(q, -128.0f), 127.0f);
            o[j] = (int)q;
        }
        if (g == 0) o0 = o; else if (g == 1) o1 = o; else if (g == 2) o2 = o; else o3 = o;
    }

    __builtin_nontemporal_store(o0, &ov[base + 0 * 256 + t]);
    __builtin_nontemporal_store(o1, &ov[base + 1 * 256 + t]);
    __builtin_nontemporal_store(o2, &ov[base + 2 * 256 + t]);
    __builtin_nontemporal_store(o3, &ov[base + 3 * 256 + t]);
}

extern "C" void kernel_launch(void* const* d_in, const int* in_sizes, int n_in,
                              void* d_out, int out_size, void* d_ws, size_t ws_size,
                              hipStream_t stream) {
    const int*   x    = (const int*)d_in[0];
    const int*   w    = (const int*)d_in[1];
    const int*   bias = (const int*)d_in[2];
    const float* s_in = (const float*)d_in[3];
    const float* s_w  = (const float*)d_in[4];
    const float* s_out= (const float*)d_in[5];
    const float* s_b  = (const float*)d_in[6];
    int* out = (int*)d_out;

    const int rows = out_size / (VPR * 4);      // B*D = 32768
    qconv1d_kernel<<<rows, 256, 0, stream>>>(x, w, bias, s_in, s_w, s_out, s_b, out);
}